// Round 8
// baseline (338.311 us; speedup 1.0000x reference)
//
#include <hip/hip_runtime.h>
#include <hip/hip_bf16.h>

// ---------- constants ----------
constexpr int Bb   = 8;
constexpr int Hh   = 96;
constexpr int Ww   = 96;
constexpr int Cc   = 192;
constexpr int WS   = 12;
constexpr int WS2  = 144;            // 12*12
constexpr int HEADS= 8;
constexpr int HD   = 24;
constexpr int NWIN = Bb * (Hh/WS) * (Ww/WS);   // 512
constexpr int Mrows= NWIN * WS2;               // 73728
constexpr int QKVN = 3 * Cc;                   // 576

typedef __bf16 bf16x8 __attribute__((ext_vector_type(8)));
typedef float  f32x4  __attribute__((ext_vector_type(4)));

constexpr int LDP = 40;   // GEMM LDS row stride (bf16): 80B -> 2-way bank aliasing = free

__device__ __forceinline__ float us2f(unsigned short u) {
    unsigned int i = ((unsigned int)u) << 16;
    float f; __builtin_memcpy(&f, &i, 4);
    return f;
}
__device__ __forceinline__ unsigned short f2us(float f) {
    unsigned int i; __builtin_memcpy(&i, &f, 4);
    unsigned int lsb = (i >> 16) & 1u;
    i += 0x7fffu + lsb;
    return (unsigned short)(i >> 16);
}

// ---------------------------------------------------------------
// Kernel 1 (MFMA): qkv = window_partition(x) @ qkv_w^T + qkv_b
// 1D grid 5184 = 8 XCD chunks of 648; swizzle makes each XCD own
// contiguous m-tiles (all 9 n-blocks) -> A-tile fetched once/XCD.
// ---------------------------------------------------------------
__global__ __launch_bounds__(256) void qkv_gemm(
        const float* __restrict__ x,      // f32 [B*N*C]
        const float* __restrict__ w,      // f32 [576][192]
        const float* __restrict__ bias,   // f32 [576]
        unsigned short* __restrict__ qkv) // bf16 [Mrows][576]
{
    __shared__ __bf16 As[128][LDP];
    __shared__ __bf16 Bs[64][LDP];

    const int tid = threadIdx.x;
    const int bid = blockIdx.x;                      // 0..5183
    const int swz = (bid & 7) * 648 + (bid >> 3);    // bijective XCD chunking
    const int n0  = (swz % 9) * 64;
    const int m0  = (swz / 9) * 128;

    const int sa_row = tid >> 1;
    const int sa_ks  = (tid & 1) * 16;
    const int sb_row = tid >> 2;
    const int sb_ks  = (tid & 3) * 8;

    const int m    = m0 + sa_row;
    const int widx = m / WS2;
    const int pos  = m % WS2;
    const int b    = widx >> 6;
    const int wi   = (widx >> 3) & 7;
    const int wj   = widx & 7;
    const long xrow = ((long)((b * Hh + wi * WS + pos / WS) * Ww + wj * WS + pos % WS)) * Cc;
    const long brow = (long)(n0 + sb_row) * Cc;

    const int lane = tid & 63;
    const int wid  = tid >> 6;
    const int wm   = wid >> 1;
    const int wn   = wid & 1;
    const int frow = lane & 15;
    const int kblk = lane >> 4;

    f32x4 acc[4][2];
    #pragma unroll
    for (int i = 0; i < 4; ++i)
        #pragma unroll
        for (int j = 0; j < 2; ++j)
            acc[i][j] = f32x4{0.f, 0.f, 0.f, 0.f};

    for (int k0 = 0; k0 < Cc; k0 += 32) {
        {
            const float* g = x + xrow + k0 + sa_ks;
            float4 f0 = *reinterpret_cast<const float4*>(g);
            float4 f1 = *reinterpret_cast<const float4*>(g + 4);
            float4 f2 = *reinterpret_cast<const float4*>(g + 8);
            float4 f3 = *reinterpret_cast<const float4*>(g + 12);
            bf16x8 p0, p1;
            p0[0]=(__bf16)f0.x; p0[1]=(__bf16)f0.y; p0[2]=(__bf16)f0.z; p0[3]=(__bf16)f0.w;
            p0[4]=(__bf16)f1.x; p0[5]=(__bf16)f1.y; p0[6]=(__bf16)f1.z; p0[7]=(__bf16)f1.w;
            p1[0]=(__bf16)f2.x; p1[1]=(__bf16)f2.y; p1[2]=(__bf16)f2.z; p1[3]=(__bf16)f2.w;
            p1[4]=(__bf16)f3.x; p1[5]=(__bf16)f3.y; p1[6]=(__bf16)f3.z; p1[7]=(__bf16)f3.w;
            *reinterpret_cast<bf16x8*>(&As[sa_row][sa_ks])     = p0;
            *reinterpret_cast<bf16x8*>(&As[sa_row][sa_ks + 8]) = p1;
        }
        {
            const float* g = w + brow + k0 + sb_ks;
            float4 f0 = *reinterpret_cast<const float4*>(g);
            float4 f1 = *reinterpret_cast<const float4*>(g + 4);
            bf16x8 p0;
            p0[0]=(__bf16)f0.x; p0[1]=(__bf16)f0.y; p0[2]=(__bf16)f0.z; p0[3]=(__bf16)f0.w;
            p0[4]=(__bf16)f1.x; p0[5]=(__bf16)f1.y; p0[6]=(__bf16)f1.z; p0[7]=(__bf16)f1.w;
            *reinterpret_cast<bf16x8*>(&Bs[sb_row][sb_ks]) = p0;
        }
        __syncthreads();

        bf16x8 a0 = *reinterpret_cast<const bf16x8*>(&As[wm*64 +  0 + frow][kblk*8]);
        bf16x8 a1 = *reinterpret_cast<const bf16x8*>(&As[wm*64 + 16 + frow][kblk*8]);
        bf16x8 a2 = *reinterpret_cast<const bf16x8*>(&As[wm*64 + 32 + frow][kblk*8]);
        bf16x8 a3 = *reinterpret_cast<const bf16x8*>(&As[wm*64 + 48 + frow][kblk*8]);
        bf16x8 b0 = *reinterpret_cast<const bf16x8*>(&Bs[wn*32 +  0 + frow][kblk*8]);
        bf16x8 b1 = *reinterpret_cast<const bf16x8*>(&Bs[wn*32 + 16 + frow][kblk*8]);

        acc[0][0] = __builtin_amdgcn_mfma_f32_16x16x32_bf16(a0, b0, acc[0][0], 0, 0, 0);
        acc[0][1] = __builtin_amdgcn_mfma_f32_16x16x32_bf16(a0, b1, acc[0][1], 0, 0, 0);
        acc[1][0] = __builtin_amdgcn_mfma_f32_16x16x32_bf16(a1, b0, acc[1][0], 0, 0, 0);
        acc[1][1] = __builtin_amdgcn_mfma_f32_16x16x32_bf16(a1, b1, acc[1][1], 0, 0, 0);
        acc[2][0] = __builtin_amdgcn_mfma_f32_16x16x32_bf16(a2, b0, acc[2][0], 0, 0, 0);
        acc[2][1] = __builtin_amdgcn_mfma_f32_16x16x32_bf16(a2, b1, acc[2][1], 0, 0, 0);
        acc[3][0] = __builtin_amdgcn_mfma_f32_16x16x32_bf16(a3, b0, acc[3][0], 0, 0, 0);
        acc[3][1] = __builtin_amdgcn_mfma_f32_16x16x32_bf16(a3, b1, acc[3][1], 0, 0, 0);
        __syncthreads();
    }

    const int lrow = lane >> 4, lcol = lane & 15;
    #pragma unroll
    for (int fn = 0; fn < 2; ++fn) {
        const int c = n0 + wn*32 + fn*16 + lcol;
        const float bv = bias[c];
        #pragma unroll
        for (int fm = 0; fm < 4; ++fm) {
            const int rbase = m0 + wm*64 + fm*16 + lrow*4;
            #pragma unroll
            for (int r = 0; r < 4; ++r)
                qkv[(long)(rbase + r) * QKVN + c] = f2us(acc[fm][fn][r] + bv);
        }
    }
}

// ---------------------------------------------------------------
// Kernel 2 (MFMA): per-(window, head) attention — round-6 version
// (LDS-staged K/Q/V; proven 105 us).
// ---------------------------------------------------------------
__global__ __launch_bounds__(192) void attn_kernel(
        const unsigned short* __restrict__ qkv,    // bf16 [Mrows][576]
        const float* __restrict__ btab,            // f32 [529][8]
        unsigned short* __restrict__ aout)         // bf16 [Mrows][192]
{
    __shared__ unsigned short Klds[WS2][40];
    __shared__ unsigned short Qlds[WS2][40];
    __shared__ unsigned short Vt[32][168];
    __shared__ unsigned short Pl[3][16][168];
    __shared__ float Bh[529];
    __shared__ unsigned short klut[WS2];
    __shared__ float l_inv[3][16];

    const int blk  = blockIdx.x;
    const int win  = blk >> 3;
    const int head = blk & 7;
    const int tid  = threadIdx.x;

    const long base = (long)win * WS2 * QKVN;
    const int hoff  = head * HD;

    if (tid < WS2) {
        const uint4* qs = reinterpret_cast<const uint4*>(qkv + base + (long)tid * QKVN + hoff);
        const uint4* ks = reinterpret_cast<const uint4*>(qkv + base + (long)tid * QKVN + Cc + hoff);
        const uint4* vs = reinterpret_cast<const uint4*>(qkv + base + (long)tid * QKVN + 2*Cc + hoff);
        uint4 q0 = qs[0], q1 = qs[1], q2 = qs[2];
        uint4 k0 = ks[0], k1 = ks[1], k2 = ks[2];
        uint4 v0 = vs[0], v1 = vs[1], v2 = vs[2];
        *reinterpret_cast<uint4*>(&Qlds[tid][0])  = q0;
        *reinterpret_cast<uint4*>(&Qlds[tid][8])  = q1;
        *reinterpret_cast<uint4*>(&Qlds[tid][16]) = q2;
        *reinterpret_cast<uint4*>(&Qlds[tid][24]) = uint4{0,0,0,0};
        *reinterpret_cast<uint4*>(&Klds[tid][0])  = k0;
        *reinterpret_cast<uint4*>(&Klds[tid][8])  = k1;
        *reinterpret_cast<uint4*>(&Klds[tid][16]) = k2;
        *reinterpret_cast<uint4*>(&Klds[tid][24]) = uint4{0,0,0,0};
        unsigned short vr[24];
        __builtin_memcpy(&vr[0],  &v0, 16);
        __builtin_memcpy(&vr[8],  &v1, 16);
        __builtin_memcpy(&vr[16], &v2, 16);
        #pragma unroll
        for (int d = 0; d < HD; ++d)
            Vt[d][tid] = vr[d];
    }
    for (int e = tid; e < 8 * 160; e += 192)
        Vt[24 + e / 160][e % 160] = 0;
    for (int e = tid; e < 24 * 16; e += 192)
        Vt[e / 16][144 + (e & 15)] = 0;
    for (int e = tid; e < 529; e += 192)
        Bh[e] = btab[e * HEADS + head];
    if (tid < WS2)
        klut[tid] = (unsigned short)((tid / WS) * 23 + (tid % WS));
    __syncthreads();

    const int wv   = tid >> 6;
    const int lane = tid & 63;
    const int qcol = lane & 15;
    const int g    = lane >> 4;

    #pragma unroll
    for (int i = 0; i < 4; ++i) {
        const int e = lane + i * 64;
        Pl[wv][e >> 4][144 + (e & 15)] = 0;
    }

    const float scale = 0.2041241452319315f;   // 1/sqrt(24)

    #pragma unroll
    for (int ti = 0; ti < 3; ++ti) {
        const int qt = wv * 3 + ti;

        bf16x8 qb = *reinterpret_cast<const bf16x8*>(&Qlds[qt*16 + qcol][g*8]);
        f32x4 s[9];
        #pragma unroll
        for (int t = 0; t < 9; ++t) {
            bf16x8 ka = *reinterpret_cast<const bf16x8*>(&Klds[t*16 + qcol][g*8]);
            s[t] = __builtin_amdgcn_mfma_f32_16x16x32_bf16(ka, qb,
                     f32x4{0.f,0.f,0.f,0.f}, 0, 0, 0);
        }

        const int qpos = qt * 16 + qcol;
        const float bbase = (float)((qpos / WS + 11) * 23 + (qpos % WS + 11));
        float sv[9][4];
        float mx = -1e30f;
        #pragma unroll
        for (int t = 0; t < 9; ++t)
            #pragma unroll
            for (int r = 0; r < 4; ++r) {
                const int kv = t*16 + g*4 + r;
                const int rel = (int)bbase - (int)klut[kv];
                const float v = s[t][r] * scale + Bh[rel];
                sv[t][r] = v;
                mx = fmaxf(mx, v);
            }
        mx = fmaxf(mx, __shfl_xor(mx, 16));
        mx = fmaxf(mx, __shfl_xor(mx, 32));
        float sum = 0.f;
        #pragma unroll
        for (int t = 0; t < 9; ++t)
            #pragma unroll
            for (int r = 0; r < 4; ++r) {
                const float p = __expf(sv[t][r] - mx);
                sv[t][r] = p;
                sum += p;
            }
        sum += __shfl_xor(sum, 16);
        sum += __shfl_xor(sum, 32);
        if (g == 0)
            l_inv[wv][qcol] = 1.f / sum;

        #pragma unroll
        for (int t = 0; t < 9; ++t)
            #pragma unroll
            for (int r = 0; r < 4; ++r)
                Pl[wv][qcol][t*16 + g*4 + r] = f2us(sv[t][r]);

        f32x4 o0 = {0.f,0.f,0.f,0.f}, o1 = {0.f,0.f,0.f,0.f};
        #pragma unroll
        for (int ks = 0; ks < 5; ++ks) {
            bf16x8 pa  = *reinterpret_cast<const bf16x8*>(&Pl[wv][qcol][ks*32 + g*8]);
            bf16x8 vb0 = *reinterpret_cast<const bf16x8*>(&Vt[qcol     ][ks*32 + g*8]);
            bf16x8 vb1 = *reinterpret_cast<const bf16x8*>(&Vt[16 + qcol][ks*32 + g*8]);
            o0 = __builtin_amdgcn_mfma_f32_16x16x32_bf16(pa, vb0, o0, 0, 0, 0);
            o1 = __builtin_amdgcn_mfma_f32_16x16x32_bf16(pa, vb1, o1, 0, 0, 0);
        }

        #pragma unroll
        for (int idx = 0; idx < 4; ++idx) {
            const int qrow = qt*16 + g*4 + idx;
            const float li = l_inv[wv][g*4 + idx];
            const long ob = (long)(win * WS2 + qrow) * Cc + hoff;
            aout[ob + qcol] = f2us(o0[idx] * li);
            if (qcol < 8)
                aout[ob + 16 + qcol] = f2us(o1[idx] * li);
        }
    }
}

// ---------------------------------------------------------------
// Kernel 3 (MFMA): out = window_reverse(aout @ proj_w^T + proj_b)
// 1D grid 1728 = 8 XCD chunks of 216, same swizzle as qkv.
// ---------------------------------------------------------------
__global__ __launch_bounds__(256) void proj_gemm(
        const unsigned short* __restrict__ aout,   // bf16 [Mrows][192]
        const float* __restrict__ pw,              // f32 [192][192]
        const float* __restrict__ pb,              // f32 [192]
        float* __restrict__ out)                   // f32 [B*N*C]
{
    __shared__ __bf16 As[128][LDP];
    __shared__ __bf16 Bs[64][LDP];

    const int tid = threadIdx.x;
    const int bid = blockIdx.x;                      // 0..1727
    const int swz = (bid & 7) * 216 + (bid >> 3);
    const int n0  = (swz % 3) * 64;
    const int m0  = (swz / 3) * 128;

    const int sa_row = tid >> 1;
    const int sa_ks  = (tid & 1) * 16;
    const int sb_row = tid >> 2;
    const int sb_ks  = (tid & 3) * 8;

    const long arow = (long)(m0 + sa_row) * Cc;
    const long brow = (long)(n0 + sb_row) * Cc;

    const int lane = tid & 63;
    const int wid  = tid >> 6;
    const int wm   = wid >> 1;
    const int wn   = wid & 1;
    const int frow = lane & 15;
    const int kblk = lane >> 4;

    f32x4 acc[4][2];
    #pragma unroll
    for (int i = 0; i < 4; ++i)
        #pragma unroll
        for (int j = 0; j < 2; ++j)
            acc[i][j] = f32x4{0.f, 0.f, 0.f, 0.f};

    for (int k0 = 0; k0 < Cc; k0 += 32) {
        {
            const unsigned short* g = aout + arow + k0 + sa_ks;
            uint4 v0 = *reinterpret_cast<const uint4*>(g);
            uint4 v1 = *reinterpret_cast<const uint4*>(g + 8);
            *reinterpret_cast<uint4*>(&As[sa_row][sa_ks])     = v0;
            *reinterpret_cast<uint4*>(&As[sa_row][sa_ks + 8]) = v1;
        }
        {
            const float* g = pw + brow + k0 + sb_ks;
            float4 f0 = *reinterpret_cast<const float4*>(g);
            float4 f1 = *reinterpret_cast<const float4*>(g + 4);
            bf16x8 p0;
            p0[0]=(__bf16)f0.x; p0[1]=(__bf16)f0.y; p0[2]=(__bf16)f0.z; p0[3]=(__bf16)f0.w;
            p0[4]=(__bf16)f1.x; p0[5]=(__bf16)f1.y; p0[6]=(__bf16)f1.z; p0[7]=(__bf16)f1.w;
            *reinterpret_cast<bf16x8*>(&Bs[sb_row][sb_ks]) = p0;
        }
        __syncthreads();

        bf16x8 a0 = *reinterpret_cast<const bf16x8*>(&As[wm*64 +  0 + frow][kblk*8]);
        bf16x8 a1 = *reinterpret_cast<const bf16x8*>(&As[wm*64 + 16 + frow][kblk*8]);
        bf16x8 a2 = *reinterpret_cast<const bf16x8*>(&As[wm*64 + 32 + frow][kblk*8]);
        bf16x8 a3 = *reinterpret_cast<const bf16x8*>(&As[wm*64 + 48 + frow][kblk*8]);
        bf16x8 b0 = *reinterpret_cast<const bf16x8*>(&Bs[wn*32 +  0 + frow][kblk*8]);
        bf16x8 b1 = *reinterpret_cast<const bf16x8*>(&Bs[wn*32 + 16 + frow][kblk*8]);

        acc[0][0] = __builtin_amdgcn_mfma_f32_16x16x32_bf16(a0, b0, acc[0][0], 0, 0, 0);
        acc[0][1] = __builtin_amdgcn_mfma_f32_16x16x32_bf16(a0, b1, acc[0][1], 0, 0, 0);
        acc[1][0] = __builtin_amdgcn_mfma_f32_16x16x32_bf16(a1, b0, acc[1][0], 0, 0, 0);
        acc[1][1] = __builtin_amdgcn_mfma_f32_16x16x32_bf16(a1, b1, acc[1][1], 0, 0, 0);
        acc[2][0] = __builtin_amdgcn_mfma_f32_16x16x32_bf16(a2, b0, acc[2][0], 0, 0, 0);
        acc[2][1] = __builtin_amdgcn_mfma_f32_16x16x32_bf16(a2, b1, acc[2][1], 0, 0, 0);
        acc[3][0] = __builtin_amdgcn_mfma_f32_16x16x32_bf16(a3, b0, acc[3][0], 0, 0, 0);
        acc[3][1] = __builtin_amdgcn_mfma_f32_16x16x32_bf16(a3, b1, acc[3][1], 0, 0, 0);
        __syncthreads();
    }

    const int lrow = lane >> 4, lcol = lane & 15;

    #pragma unroll
    for (int fm = 0; fm < 4; ++fm) {
        #pragma unroll
        for (int r = 0; r < 4; ++r) {
            const int mrow = m0 + wm*64 + fm*16 + lrow*4 + r;
            const int widx = mrow / WS2;
            const int pos  = mrow % WS2;
            const int b    = widx >> 6;
            const int wi   = (widx >> 3) & 7;
            const int wj   = widx & 7;
            const int h    = wi * WS + pos / WS;
            const int w_   = wj * WS + pos % WS;
            const long orow = ((long)(b * Hh + h) * Ww + w_) * Cc;

            #pragma unroll
            for (int fn = 0; fn < 2; ++fn) {
                const int c = n0 + wn*32 + fn*16 + lcol;
                out[orow + c] = acc[fm][fn][r] + pb[c];
            }
        }
    }
}

// ---------------------------------------------------------------
// Kernel 4: out += (depthwise3x3(x) + lb) * lsc * mask
// ---------------------------------------------------------------
__global__ __launch_bounds__(256) void lpe_add(
        const float* __restrict__ x,               // f32 [B*H*W*C]
        const float* __restrict__ lw,              // f32 [192][9]
        const float* __restrict__ lb,              // f32 [192]
        const float* __restrict__ lsc,             // f32 [1]
        const float* __restrict__ mask,            // f32 [B*H*W]
        float* __restrict__ out)                   // f32 [B*H*W*C]
{
    __shared__ float lwt[9][Cc];
    __shared__ float lbs[Cc];

    const int tid = threadIdx.x;
    for (int e = tid; e < Cc * 9; e += 256) {
        const int c = e / 9, tap = e % 9;
        lwt[tap][c] = lw[e];
    }
    for (int e = tid; e < Cc; e += 256)
        lbs[e] = lb[e];
    __syncthreads();

    const float ls = lsc[0];
    const long idx = (long)blockIdx.x * 256 + tid;
    const int c  = ((int)(idx % 48)) * 4;
    const int p  = (int)(idx / 48);
    const int w_ = p % Ww;
    const int h  = (p / Ww) % Hh;

    float4 acc = *reinterpret_cast<const float4*>(&lbs[c]);
    #pragma unroll
    for (int kh = -1; kh <= 1; ++kh) {
        const int hh = h + kh;
        if (hh < 0 || hh >= Hh) continue;
        #pragma unroll
        for (int kw = -1; kw <= 1; ++kw) {
            const int ww = w_ + kw;
            if (ww < 0 || ww >= Ww) continue;
            const float4 xv = *reinterpret_cast<const float4*>(
                x + ((long)p + kh * Ww + kw) * Cc + c);
            const float4 wv = *reinterpret_cast<const float4*>(&lwt[(kh+1)*3 + (kw+1)][c]);
            acc.x += xv.x * wv.x;
            acc.y += xv.y * wv.y;
            acc.z += xv.z * wv.z;
            acc.w += xv.w * wv.w;
        }
    }
    const float mv = mask[p] * ls;
    float* op = out + (long)p * Cc + c;
    float4 o = *reinterpret_cast<const float4*>(op);
    o.x += acc.x * mv;
    o.y += acc.y * mv;
    o.z += acc.z * mv;
    o.w += acc.w * mv;
    *reinterpret_cast<float4*>(op) = o;
}

// ---------------------------------------------------------------
extern "C" void kernel_launch(void* const* d_in, const int* in_sizes, int n_in,
                              void* d_out, int out_size, void* d_ws, size_t ws_size,
                              hipStream_t stream) {
    const float* x    = (const float*)d_in[0];
    const float* mask = (const float*)d_in[1];
    const float* qw   = (const float*)d_in[2];
    const float* qb   = (const float*)d_in[3];
    const float* pw   = (const float*)d_in[4];
    const float* pb   = (const float*)d_in[5];
    const float* lw   = (const float*)d_in[6];
    const float* lb   = (const float*)d_in[7];
    const float* lsc  = (const float*)d_in[8];
    const float* btab = (const float*)d_in[9];

    unsigned short* qkv  = (unsigned short*)d_ws;                // bf16 [73728][576]
    unsigned short* aout = qkv + (size_t)Mrows * QKVN;           // bf16 [73728][192]

    qkv_gemm<<<dim3(5184), dim3(256), 0, stream>>>(x, qw, qb, qkv);
    attn_kernel<<<dim3(NWIN * HEADS), dim3(192), 0, stream>>>(qkv, btab, aout);
    proj_gemm<<<dim3(1728), dim3(256), 0, stream>>>(aout, pw, pb, (float*)d_out);
    lpe_add<<<dim3((Mrows * 48) / 256), dim3(256), 0, stream>>>(x, lw, lb, lsc, mask,
                                                                (float*)d_out);
}